// Round 7
// baseline (1493.330 us; speedup 1.0000x reference)
//
#include <hip/hip_runtime.h>

// HMM forward (CgpHmmCell): B=512, T=4096, S=64, M=125.
// Round 24: MEASUREMENT ROUND -- read-only bandwidth probe + unchanged R18.
// Six structurally different extraction variants (R18 ping-pong, R19 depth-4,
// R20 kernel split, R21 temporal phases, R22 producer/consumer waves, R23
// aligned+scatter) ALL land at extraction ~270-290us = 3.8-4.0 TB/s read.
// Every theory (LDS conflicts, register-bound depth, latency closed-loop,
// page locality, alignment, extraction idiom) failed a prediction. The one
// quantity never measured: READ-ONLY HBM ceiling. The 6.3 TB/s reference is
// a float4 COPY (R+W); fills show 6.4 write-only; no read-only number
// exists. This round launches (1) read_probe: grid-stride dwordx4 read-
// reduce over the same 1.05 GB input, 2048 blocks x 256 thr (8192 waves,
// 32/CU, unroll-4 MLP), checksum stored to d_ws (scratch, poisoned by
// harness anyway; guarded by ws_size; asm keep-alive fallback); then (2)
// the byte-identical R18 kernel (1296.46us, absmax 0.0). Probe time =
// dur_us - 1296. Pre-committed read: <=210us -> read path fine, kernel
// structure guilty, bisect next; >=250us -> kernel has been at the read
// roofline all along -> revert probe and declare roofline.

#define BATCH 512
#define T 4096
#define S 64
#define M 125
#define BMS 68     // BmL row stride in dwords: 68%32=4 -> 8 bank phases, 16B-aligned
#define NPACK 10   // 2 burn + 8 accumulate (chunk = 64 steps)
#define BURNP 2
#define WPB 4
#define RB 56.0f
#define SCALEF 7.205759403792794e16f   // 2^56

typedef __attribute__((ext_vector_type(8))) short bf16x8;
typedef __attribute__((ext_vector_type(4))) float f32x4;
typedef float f32x4u __attribute__((ext_vector_type(4), aligned(4)));  // 4-B-aligned vec4

union BFU { unsigned u[4]; bf16x8 v; };

__device__ __forceinline__ unsigned pk_trunc(float a, float b) {
    return (__float_as_uint(b) & 0xFFFF0000u) | (__float_as_uint(a) >> 16);
}
__device__ __forceinline__ unsigned pk_rne(float a, float b) {
    unsigned ua = __float_as_uint(a); ua += 0x7FFFu + ((ua >> 16) & 1u);
    unsigned ub = __float_as_uint(b); ub += 0x7FFFu + ((ub >> 16) & 1u);
    return (ub & 0xFFFF0000u) | (ua >> 16);
}

// =================== read-only BW probe (measurement only) ===================
__global__ __launch_bounds__(256) void read_probe(const float* __restrict__ x,
                                                  unsigned* __restrict__ sink) {
    const size_t N = (size_t)BATCH * T * M;           // 262,144,000 dwords
    const size_t stride = (size_t)gridDim.x * 256 * 4;
    size_t i = ((size_t)blockIdx.x * 256 + threadIdx.x) * 4;
    unsigned acc = 0;
    // 65,536,000 vec4s / 524,288 lanes = 125 iters exactly; unroll 4 -> MLP 4.
#pragma unroll 4
    for (; i + 3 < N; i += stride) {
        f32x4 v = *(const f32x4*)&x[i];
        acc += __float_as_uint(v.x) + __float_as_uint(v.y) +
               __float_as_uint(v.z) + __float_as_uint(v.w);
    }
    if (sink) {
        if ((threadIdx.x & 63) == 0)
            sink[blockIdx.x * 4 + (threadIdx.x >> 6)] = acc;
    } else {
        asm volatile("" :: "v"(acc));                 // keep reads live
    }
}

// ==================== R18 fused kernel (byte-identical) ====================
__global__ __launch_bounds__(256) void hmm_fused(const float* __restrict__ x,
                                                 const float* __restrict__ Iv,
                                                 const float* __restrict__ A,
                                                 const float* __restrict__ Bm,
                                                 float* __restrict__ out) {
    __shared__ __align__(16) float BmL[M * BMS];               // 34000 B, stride-68 rows
    __shared__ __align__(16) float ILds[S];
    __shared__ unsigned long long ulds[WPB * 16 * NPACK];      // 5120 B

    const int tid = threadIdx.x, wv = tid >> 6, lane = tid & 63;
    const int s = lane & 15, g = lane >> 4;

    for (int i = tid; i < M * S; i += WPB * 64)
        BmL[(i >> 6) * BMS + (i & 63)] = Bm[i];
    if (tid < S) ILds[tid] = Iv[tid];
    __syncthreads();

    // A^T fragments under pi: slot (kf,g,j2,e) holds A[p0+e][16mt+s],
    // p0 = 32kf + 16*(j2>>1) + 4g + 2*(j2&1).
    BFU Af[4][2];
#pragma unroll
    for (int mt = 0; mt < 4; ++mt)
#pragma unroll
        for (int kf = 0; kf < 2; ++kf)
#pragma unroll
            for (int j2 = 0; j2 < 4; ++j2) {
                int p0 = 32 * kf + 16 * (j2 >> 1) + 4 * g + 2 * (j2 & 1);
                Af[mt][kf].u[j2] = pk_rne(A[(size_t)p0 * S + mt * 16 + s],
                                          A[(size_t)(p0 + 1) * S + mt * 16 + s]);
            }

    const int W = blockIdx.x * WPB + wv;   // 0..2047
    const int seq = W >> 2, wq = W & 3;    // 4 waves per sequence
    const float* xs = x + (size_t)seq * T * M;
    unsigned long long* myu = &ulds[wv * 16 * NPACK];
    const int base = wq * 1024;            // wave's first row (seq-relative)

    const int rel = lane & 31, hf = lane >> 5;
    const unsigned coff = (rel < 31) ? 4u * (unsigned)rel : 121u;  // dword in row

    f32x4u bufP[8], bufQ[8];               // ping-pong: 2 x 16 rows in flight

    auto issue16 = [&](f32x4u (&bf)[8], int r0a, int r0b) {
#pragma unroll
        for (int j = 0; j < 4; ++j) {
            unsigned ra = (unsigned)((r0a + 2 * j + hf) * 125) + coff;
            unsigned rb = (unsigned)((r0b + 2 * j + hf) * 125) + coff;
            bf[j]     = *(const f32x4u*)&xs[ra];
            bf[4 + j] = *(const f32x4u*)&xs[rb];
        }
    };
    auto ext8 = [&](const f32x4u (&bf)[8], int b) -> unsigned long long {
        unsigned long long acc = 0;
#pragma unroll
        for (int j = 0; j < 4; ++j) {
            f32x4u v = bf[b * 4 + j];
            bool nz = (v.x != 0.f) || (v.y != 0.f) || (v.z != 0.f) || (v.w != 0.f);
            unsigned li = (v.x != 0.f) ? 0u : ((v.y != 0.f) ? 1u : ((v.z != 0.f) ? 2u : 3u));
            unsigned cand = coff + li;                 // dword index of first nz here
            unsigned long long m = __ballot(nz);       // one-hot => both halves nonzero
            unsigned l0 = (unsigned)__builtin_ctzll(m & 0xffffffffull);
            unsigned l1 = (unsigned)__builtin_ctzll(m >> 32);
            unsigned o0 = __builtin_amdgcn_readlane(cand, l0);        // row 2j
            unsigned o1 = __builtin_amdgcn_readlane(cand, 32 + l1);   // row 2j+1
            acc |= ((unsigned long long)o0 << (16 * j)) |
                   ((unsigned long long)o1 << (16 * j + 8));
        }
        return acc;
    };
    auto put = [&](int st, int pt, unsigned long long v) {
        if (lane == st) myu[st * NPACK + pt] = v;
    };

    // ---- Phase A: PRE (boundary burn) + K (rel 48..56) + L (rel 56..64) ----
    {
        int pa = base - 16, pb = base - 8;
        if (pa < 0) pa = 0;                // wq==0: garbage; chunk0 exact-init
        if (pb < 0) pb = 0;
        issue16(bufP, pa, pb);
        for (int gi = 0; gi <= 16; ++gi) {
            unsigned long long a0 = ext8(bufP, 0), a1 = ext8(bufP, 1);
            if (gi < 16) {                                   // issue next group
                int ni = gi + 1;
                if (ni <= 8) { int i = ni - 1; issue16(bufP, base + (2 * i) * 64 + 48, base + (2 * i + 1) * 64 + 48); }
                else         { int i = ni - 9; issue16(bufP, base + (2 * i) * 64 + 56, base + (2 * i + 1) * 64 + 56); }
            } else {
                issue16(bufP, base + 0, base + 64);          // step 0 (p0,k0)
            }
            if (gi == 0) {                                   // PRE -> (0,p0),(0,p1)
                put(0, 0, a0); put(0, 1, a1);
            } else if (gi <= 8) {                            // K: (c,p8) & (c+1,p0)
                int i = gi - 1;
                put(2 * i, 8, a0);     put(2 * i + 1, 0, a0);
                put(2 * i + 1, 8, a1); if (2 * i + 2 <= 15) put(2 * i + 2, 0, a1);
            } else {                                         // L: (c,p9) & (c+1,p1)
                int i = gi - 9;
                put(2 * i, 9, a0);     put(2 * i + 1, 1, a0);
                put(2 * i + 1, 9, a1); if (2 * i + 2 <= 15) put(2 * i + 2, 1, a1);
            }
        }
        issue16(bufQ, base + 128, base + 192);               // step 1 (p0,k1)
    }

    // ---- Phase B: scan packs 0..9; packs 0..5 interleave extraction ----
    BFU Bf[2];
#pragma unroll
    for (int kf = 0; kf < 2; ++kf)
#pragma unroll
        for (int j = 0; j < 4; ++j) Bf[kf].u[j] = 0x3F803F80u;  // 1.0 burn seed

    float S0v = 0.f, swv = 1.f;

    for (int p = 0; p < NPACK; ++p) {
        unsigned long long uv = myu[s * NPACK + p];   // this pack's o-bytes
        const bool exsl = (p < 6);
#pragma unroll
        for (int k = 0; k < 8; ++k) {
            // --- MFMA section first (issue, don't consume yet) ---
            const int o = (int)(uv & 255ull);
            uv >>= 8;
            const float* br = &BmL[o * BMS];          // per-stream row, bank-phased
            f32x4 E[4], z0[4], z1[4];
#pragma unroll
            for (int mt = 0; mt < 4; ++mt) {
                E[mt] = *(const f32x4*)&br[mt * 16 + g * 4];
                f32x4 zr = {0.f, 0.f, 0.f, 0.f};
                z0[mt] = __builtin_amdgcn_mfma_f32_16x16x32_bf16(Af[mt][0].v, Bf[0].v, zr, 0, 0, 0);
                z1[mt] = __builtin_amdgcn_mfma_f32_16x16x32_bf16(Af[mt][1].v, Bf[1].v, zr, 0, 0, 0);
            }
            // --- extraction (vmcnt wait overlaps MFMAs); distance-2 refill ---
            if (exsl) {
                unsigned long long a0, a1;
                // k is compile-time (unrolled): buffer parity = k&1
                if ((k & 1) == 0) { a0 = ext8(bufP, 0); a1 = ext8(bufP, 1); }
                else              { a0 = ext8(bufQ, 0); a1 = ext8(bufQ, 1); }
                int k2 = k + 2, p2 = p;
                bool ok = true;
                if (k2 >= 8) { k2 -= 8; p2 = p + 1; ok = (p2 < 6); }
                if (ok) {
                    int r0a = base + (2 * k2) * 64 + 8 * p2;
                    if ((k & 1) == 0) issue16(bufP, r0a, r0a + 64);
                    else              issue16(bufQ, r0a, r0a + 64);
                }
                put(2 * k, p + 2, a0);
                put(2 * k + 1, p + 2, a1);
            }
            // --- consume MFMA results ---
            float w[4][4];
#pragma unroll
            for (int mt = 0; mt < 4; ++mt)
#pragma unroll
                for (int r = 0; r < 4; ++r) w[mt][r] = (z0[mt][r] + z1[mt][r]) * E[mt][r];
            if (p == BURNP && k == 0 && wq == 0) {    // exact t=0 init of chunk 0
                const bool c0 = (s == 0);
#pragma unroll
                for (int mt = 0; mt < 4; ++mt)
#pragma unroll
                    for (int r = 0; r < 4; ++r)
                        w[mt][r] = c0 ? ILds[mt * 16 + g * 4 + r] * E[mt][r] : w[mt][r];
            }
            if (k == 7 && (p == BURNP - 1 || p == NPACK - 1)) {  // mass (pre-scale)
                float swl = 0.f;
#pragma unroll
                for (int mt = 0; mt < 4; ++mt)
#pragma unroll
                    for (int r = 0; r < 4; ++r) swl += w[mt][r];
                swl += __shfl_xor(swl, 16);
                swl += __shfl_xor(swl, 32);
                swv = swl;
            }
            // zero-shuffle C->B under pi; constant 2^56 rescale at k==7
#pragma unroll
            for (int kf = 0; kf < 2; ++kf)
#pragma unroll
                for (int j2 = 0; j2 < 4; ++j2) {
                    int mt = 2 * kf + (j2 >> 1), pr = j2 & 1;
                    float v0 = w[mt][2 * pr], v1 = w[mt][2 * pr + 1];
                    if (k == 7) { v0 *= SCALEF; v1 *= SCALEF; }
                    Bf[kf].u[j2] = pk_trunc(v0, v1);
                }
        }
        if (p == BURNP - 1) {
            // exponents: burn mass carries 1*RB, final carries (NPACK-1)*RB
            const bool ch0 = (wq == 0) && (s == 0);
            S0v = ch0 ? ((float)(NPACK - 1 - BURNP) * RB)
                      : (__log2f(swv) + (float)(NPACK - BURNP) * RB);
        }
    }

    float tot = __log2f(swv) - S0v;
    // sum over the 16 streams (s-dim); g-lanes hold duplicates
    tot += __shfl_xor(tot, 1);
    tot += __shfl_xor(tot, 2);
    tot += __shfl_xor(tot, 4);
    tot += __shfl_xor(tot, 8);
    if (lane == 0)
        atomicAdd(out + seq, tot * 0.6931471805599453f);
}

extern "C" void kernel_launch(void* const* d_in, const int* in_sizes, int n_in,
                              void* d_out, int out_size, void* d_ws, size_t ws_size,
                              hipStream_t stream) {
    const float* x  = (const float*)d_in[0];   // [B,T,M] one-hot
    const float* I  = (const float*)d_in[1];   // [1,S]
    const float* A  = (const float*)d_in[2];   // [S,S]
    const float* Bm = (const float*)d_in[3];   // [M,S]
    float* out = (float*)d_out;                // [B,1]

    hipMemsetAsync(out, 0, (size_t)out_size * sizeof(float), stream);

    // Measurement probe: pure read-only stream over x (1.05 GB).
    unsigned* sink = (d_ws != nullptr && ws_size >= 2048u * 4u * sizeof(unsigned))
                         ? (unsigned*)d_ws : nullptr;
    read_probe<<<2048, 256, 0, stream>>>(x, sink);

    hmm_fused<<<(BATCH * 4) / WPB, WPB * 64, 0, stream>>>(x, I, A, Bm, out);  // 2048 waves
}

// Round 8
// 1326.530 us; speedup vs baseline: 1.1257x; 1.1257x over previous
//
#include <hip/hip_runtime.h>

// HMM forward (CgpHmmCell): B=512, T=4096, S=64, M=125.
// Round 25: PROBE-SHAPED EXTRACTION -> ws, + R20 SCAN. R24 measured the
// read-only ceiling: 197us for 1.05GB = 5.3 TB/s (8192-wave grid-stride
// dwordx4 probe). Our integrated extraction runs 3.9 TB/s (74%); the six
// structural nulls were benchmarked against a fictitious 6.3 copy number.
// The only 5.3 TB/s structure ever measured is the probe itself, so K1 IS
// the probe: 2048 blocks x 256 thr, grid-stride (stride=8M dwords, 125
// iters/lane exactly), unroll 4, plus per-lane bit-test (values are exactly
// 0x0/0x3F800000 -> mask from bits 29..26) and rare scattered byte-store:
// d = i+ctz(m), row = d*2199023256>>38 (exact magic /125 for d<2^28, error
// 56d/(125*2^38) < 1/125), o = d-125*row, ws[row]=o; straddle handled via
// m&(m-1) (two ones can be adjacent: o=124 then o=0 next row; never 3).
// Hit rate 3.2%/lane/iter; write traffic 2MB. K2 = R20's hmm_scan VERBATIM
// (verified absmax 0.0 in R20 with identical ws byte semantics: byte r of
// ws = o of global row r; u64 index B0+p-2, clamps match R18's pa/pb).
// Pre-committed: dur 1250-1280 -> win; 1320-1350 -> K2 guilty (~100us);
// >=1380 -> scatter payload breaks streaming. Fallback: R18 fused verbatim.

#define BATCH 512
#define T 4096
#define S 64
#define M 125
#define BMS 68     // BmL row stride in dwords: 68%32=4 -> 8 bank phases, 16B-aligned
#define NPACK 10   // 2 burn + 8 accumulate (chunk = 64 steps)
#define BURNP 2
#define WPB 4
#define RB 56.0f
#define SCALEF 7.205759403792794e16f   // 2^56

typedef __attribute__((ext_vector_type(8))) short bf16x8;
typedef __attribute__((ext_vector_type(4))) float f32x4;
typedef float f32x4u __attribute__((ext_vector_type(4), aligned(4)));  // 4-B-aligned vec4

union BFU { unsigned u[4]; bf16x8 v; };

__device__ __forceinline__ unsigned pk_trunc(float a, float b) {
    return (__float_as_uint(b) & 0xFFFF0000u) | (__float_as_uint(a) >> 16);
}
__device__ __forceinline__ unsigned pk_rne(float a, float b) {
    unsigned ua = __float_as_uint(a); ua += 0x7FFFu + ((ua >> 16) & 1u);
    unsigned ub = __float_as_uint(b); ub += 0x7FFFu + ((ub >> 16) & 1u);
    return (ub & 0xFFFF0000u) | (ua >> 16);
}

// ============ K1: probe-shaped o-byte extractor (read @ ~5.3 TB/s) ============
__global__ __launch_bounds__(256) void hmm_extract(const float* __restrict__ x,
                                                   unsigned char* __restrict__ ob) {
    const size_t N = (size_t)BATCH * T * M;           // 262,144,000 dwords
    const size_t stride = (size_t)2048 * 256 * 4;     // 8,388,608 dwords
    size_t i = ((size_t)blockIdx.x * 256 + threadIdx.x) * 4;
#pragma unroll 4
    for (; i + 3 < N; i += stride) {                  // exactly 125 iters/lane
        f32x4 v = *(const f32x4*)&x[i];
        unsigned m = ((__float_as_uint(v.x) >> 29) & 1u) |
                     ((__float_as_uint(v.y) >> 28) & 2u) |
                     ((__float_as_uint(v.z) >> 27) & 4u) |
                     ((__float_as_uint(v.w) >> 26) & 8u);
        if (m) {
            unsigned d = (unsigned)i + (unsigned)__builtin_ctz(m);
            unsigned r = (unsigned)(((unsigned long long)d * 2199023256ull) >> 38);
            ob[r] = (unsigned char)(d - 125u * r);
            unsigned m2 = m & (m - 1u);               // row-straddle 2nd hit
            if (m2) {
                unsigned d2 = (unsigned)i + (unsigned)__builtin_ctz(m2);
                unsigned r2 = (unsigned)(((unsigned long long)d2 * 2199023256ull) >> 38);
                ob[r2] = (unsigned char)(d2 - 125u * r2);
            }
        }
    }
}

// ========== K2: MFMA scan (R20 verbatim; verified absmax 0.0) ==========
__global__ __launch_bounds__(256) void hmm_scan(const unsigned long long* __restrict__ ob,
                                                const float* __restrict__ Iv,
                                                const float* __restrict__ A,
                                                const float* __restrict__ Bm,
                                                float* __restrict__ out) {
    __shared__ __align__(16) float BmL[M * BMS];               // 34000 B
    __shared__ __align__(16) float ILds[S];

    const int tid = threadIdx.x, wv = tid >> 6, lane = tid & 63;
    const int s = lane & 15, g = lane >> 4;

    for (int i = tid; i < M * S; i += WPB * 64)
        BmL[(i >> 6) * BMS + (i & 63)] = Bm[i];
    if (tid < S) ILds[tid] = Iv[tid];
    __syncthreads();

    // A^T fragments under pi (identical to fused).
    BFU Af[4][2];
#pragma unroll
    for (int mt = 0; mt < 4; ++mt)
#pragma unroll
        for (int kf = 0; kf < 2; ++kf)
#pragma unroll
            for (int j2 = 0; j2 < 4; ++j2) {
                int p0 = 32 * kf + 16 * (j2 >> 1) + 4 * g + 2 * (j2 & 1);
                Af[mt][kf].u[j2] = pk_rne(A[(size_t)p0 * S + mt * 16 + s],
                                          A[(size_t)(p0 + 1) * S + mt * 16 + s]);
            }

    const int W = blockIdx.x * WPB + wv;   // 0..2047
    const int seq = W >> 2, wq = W & 3;
    const int base = wq * 1024;
    const unsigned long long* os = ob + (size_t)seq * (T / 8);   // 512 u64 / seq
    const int B0 = (base >> 3) + 8 * s;    // u64 index of stream s's chunk start

    BFU Bf[2];
#pragma unroll
    for (int kf = 0; kf < 2; ++kf)
#pragma unroll
        for (int j = 0; j < 4; ++j) Bf[kf].u[j] = 0x3F803F80u;  // 1.0 burn seed

    float S0v = 0.f, swv = 1.f;

    int i0 = B0 - 2; if (i0 < 0) i0 = 0;
    unsigned long long uvc = os[i0];       // pack 0

    for (int p = 0; p < NPACK; ++p) {
        unsigned long long uvn = 0;
        if (p + 1 < NPACK) {               // prefetch next pack (L2/L3-resident)
            int ix = B0 + (p + 1) - 2; if (ix < 0) ix = 0;
            uvn = os[ix];
        }
        unsigned long long uv = uvc;
#pragma unroll
        for (int k = 0; k < 8; ++k) {
            const int o = (int)(uv & 255ull);
            uv >>= 8;
            const float* br = &BmL[o * BMS];          // per-stream row, bank-phased
            f32x4 E[4], z0[4], z1[4];
#pragma unroll
            for (int mt = 0; mt < 4; ++mt) {
                E[mt] = *(const f32x4*)&br[mt * 16 + g * 4];
                f32x4 zr = {0.f, 0.f, 0.f, 0.f};
                z0[mt] = __builtin_amdgcn_mfma_f32_16x16x32_bf16(Af[mt][0].v, Bf[0].v, zr, 0, 0, 0);
                z1[mt] = __builtin_amdgcn_mfma_f32_16x16x32_bf16(Af[mt][1].v, Bf[1].v, zr, 0, 0, 0);
            }
            float w[4][4];
#pragma unroll
            for (int mt = 0; mt < 4; ++mt)
#pragma unroll
                for (int r = 0; r < 4; ++r) w[mt][r] = (z0[mt][r] + z1[mt][r]) * E[mt][r];
            if (p == BURNP && k == 0 && wq == 0) {    // exact t=0 init of chunk 0
                const bool c0 = (s == 0);
#pragma unroll
                for (int mt = 0; mt < 4; ++mt)
#pragma unroll
                    for (int r = 0; r < 4; ++r)
                        w[mt][r] = c0 ? ILds[mt * 16 + g * 4 + r] * E[mt][r] : w[mt][r];
            }
            if (k == 7 && (p == BURNP - 1 || p == NPACK - 1)) {  // mass (pre-scale)
                float swl = 0.f;
#pragma unroll
                for (int mt = 0; mt < 4; ++mt)
#pragma unroll
                    for (int r = 0; r < 4; ++r) swl += w[mt][r];
                swl += __shfl_xor(swl, 16);
                swl += __shfl_xor(swl, 32);
                swv = swl;
            }
            // zero-shuffle C->B under pi; constant 2^56 rescale at k==7
#pragma unroll
            for (int kf = 0; kf < 2; ++kf)
#pragma unroll
                for (int j2 = 0; j2 < 4; ++j2) {
                    int mt = 2 * kf + (j2 >> 1), pr = j2 & 1;
                    float v0 = w[mt][2 * pr], v1 = w[mt][2 * pr + 1];
                    if (k == 7) { v0 *= SCALEF; v1 *= SCALEF; }
                    Bf[kf].u[j2] = pk_trunc(v0, v1);
                }
        }
        uvc = uvn;
        if (p == BURNP - 1) {
            const bool ch0 = (wq == 0) && (s == 0);
            S0v = ch0 ? ((float)(NPACK - 1 - BURNP) * RB)
                      : (__log2f(swv) + (float)(NPACK - BURNP) * RB);
        }
    }

    float tot = __log2f(swv) - S0v;
    tot += __shfl_xor(tot, 1);
    tot += __shfl_xor(tot, 2);
    tot += __shfl_xor(tot, 4);
    tot += __shfl_xor(tot, 8);
    if (lane == 0)
        atomicAdd(out + seq, tot * 0.6931471805599453f);
}

// ============  Fallback: R18 fused kernel (exact copy, ws-free)  ============
__global__ __launch_bounds__(256) void hmm_fused(const float* __restrict__ x,
                                                 const float* __restrict__ Iv,
                                                 const float* __restrict__ A,
                                                 const float* __restrict__ Bm,
                                                 float* __restrict__ out) {
    __shared__ __align__(16) float BmL[M * BMS];
    __shared__ __align__(16) float ILds[S];
    __shared__ unsigned long long ulds[WPB * 16 * NPACK];

    const int tid = threadIdx.x, wv = tid >> 6, lane = tid & 63;
    const int s = lane & 15, g = lane >> 4;

    for (int i = tid; i < M * S; i += WPB * 64)
        BmL[(i >> 6) * BMS + (i & 63)] = Bm[i];
    if (tid < S) ILds[tid] = Iv[tid];
    __syncthreads();

    BFU Af[4][2];
#pragma unroll
    for (int mt = 0; mt < 4; ++mt)
#pragma unroll
        for (int kf = 0; kf < 2; ++kf)
#pragma unroll
            for (int j2 = 0; j2 < 4; ++j2) {
                int p0 = 32 * kf + 16 * (j2 >> 1) + 4 * g + 2 * (j2 & 1);
                Af[mt][kf].u[j2] = pk_rne(A[(size_t)p0 * S + mt * 16 + s],
                                          A[(size_t)(p0 + 1) * S + mt * 16 + s]);
            }

    const int W = blockIdx.x * WPB + wv;
    const int seq = W >> 2, wq = W & 3;
    const float* xs = x + (size_t)seq * T * M;
    unsigned long long* myu = &ulds[wv * 16 * NPACK];
    const int base = wq * 1024;

    const int rel = lane & 31, hf = lane >> 5;
    const unsigned coff = (rel < 31) ? 4u * (unsigned)rel : 121u;

    f32x4u bufP[8], bufQ[8];

    auto issue16 = [&](f32x4u (&bf)[8], int r0a, int r0b) {
#pragma unroll
        for (int j = 0; j < 4; ++j) {
            unsigned ra = (unsigned)((r0a + 2 * j + hf) * 125) + coff;
            unsigned rb = (unsigned)((r0b + 2 * j + hf) * 125) + coff;
            bf[j]     = *(const f32x4u*)&xs[ra];
            bf[4 + j] = *(const f32x4u*)&xs[rb];
        }
    };
    auto ext8 = [&](const f32x4u (&bf)[8], int b) -> unsigned long long {
        unsigned long long acc = 0;
#pragma unroll
        for (int j = 0; j < 4; ++j) {
            f32x4u v = bf[b * 4 + j];
            bool nz = (v.x != 0.f) || (v.y != 0.f) || (v.z != 0.f) || (v.w != 0.f);
            unsigned li = (v.x != 0.f) ? 0u : ((v.y != 0.f) ? 1u : ((v.z != 0.f) ? 2u : 3u));
            unsigned cand = coff + li;
            unsigned long long m = __ballot(nz);
            unsigned l0 = (unsigned)__builtin_ctzll(m & 0xffffffffull);
            unsigned l1 = (unsigned)__builtin_ctzll(m >> 32);
            unsigned o0 = __builtin_amdgcn_readlane(cand, l0);
            unsigned o1 = __builtin_amdgcn_readlane(cand, 32 + l1);
            acc |= ((unsigned long long)o0 << (16 * j)) |
                   ((unsigned long long)o1 << (16 * j + 8));
        }
        return acc;
    };
    auto put = [&](int st, int pt, unsigned long long v) {
        if (lane == st) myu[st * NPACK + pt] = v;
    };

    {
        int pa = base - 16, pb = base - 8;
        if (pa < 0) pa = 0;
        if (pb < 0) pb = 0;
        issue16(bufP, pa, pb);
        for (int gi = 0; gi <= 16; ++gi) {
            unsigned long long a0 = ext8(bufP, 0), a1 = ext8(bufP, 1);
            if (gi < 16) {
                int ni = gi + 1;
                if (ni <= 8) { int i = ni - 1; issue16(bufP, base + (2 * i) * 64 + 48, base + (2 * i + 1) * 64 + 48); }
                else         { int i = ni - 9; issue16(bufP, base + (2 * i) * 64 + 56, base + (2 * i + 1) * 64 + 56); }
            } else {
                issue16(bufP, base + 0, base + 64);
            }
            if (gi == 0) {
                put(0, 0, a0); put(0, 1, a1);
            } else if (gi <= 8) {
                int i = gi - 1;
                put(2 * i, 8, a0);     put(2 * i + 1, 0, a0);
                put(2 * i + 1, 8, a1); if (2 * i + 2 <= 15) put(2 * i + 2, 0, a1);
            } else {
                int i = gi - 9;
                put(2 * i, 9, a0);     put(2 * i + 1, 1, a0);
                put(2 * i + 1, 9, a1); if (2 * i + 2 <= 15) put(2 * i + 2, 1, a1);
            }
        }
        issue16(bufQ, base + 128, base + 192);
    }

    BFU Bf[2];
#pragma unroll
    for (int kf = 0; kf < 2; ++kf)
#pragma unroll
        for (int j = 0; j < 4; ++j) Bf[kf].u[j] = 0x3F803F80u;

    float S0v = 0.f, swv = 1.f;

    for (int p = 0; p < NPACK; ++p) {
        unsigned long long uv = myu[s * NPACK + p];
        const bool exsl = (p < 6);
#pragma unroll
        for (int k = 0; k < 8; ++k) {
            const int o = (int)(uv & 255ull);
            uv >>= 8;
            const float* br = &BmL[o * BMS];
            f32x4 E[4], z0[4], z1[4];
#pragma unroll
            for (int mt = 0; mt < 4; ++mt) {
                E[mt] = *(const f32x4*)&br[mt * 16 + g * 4];
                f32x4 zr = {0.f, 0.f, 0.f, 0.f};
                z0[mt] = __builtin_amdgcn_mfma_f32_16x16x32_bf16(Af[mt][0].v, Bf[0].v, zr, 0, 0, 0);
                z1[mt] = __builtin_amdgcn_mfma_f32_16x16x32_bf16(Af[mt][1].v, Bf[1].v, zr, 0, 0, 0);
            }
            if (exsl) {
                unsigned long long a0, a1;
                if ((k & 1) == 0) { a0 = ext8(bufP, 0); a1 = ext8(bufP, 1); }
                else              { a0 = ext8(bufQ, 0); a1 = ext8(bufQ, 1); }
                int k2 = k + 2, p2 = p;
                bool ok = true;
                if (k2 >= 8) { k2 -= 8; p2 = p + 1; ok = (p2 < 6); }
                if (ok) {
                    int r0a = base + (2 * k2) * 64 + 8 * p2;
                    if ((k & 1) == 0) issue16(bufP, r0a, r0a + 64);
                    else              issue16(bufQ, r0a, r0a + 64);
                }
                put(2 * k, p + 2, a0);
                put(2 * k + 1, p + 2, a1);
            }
            float w[4][4];
#pragma unroll
            for (int mt = 0; mt < 4; ++mt)
#pragma unroll
                for (int r = 0; r < 4; ++r) w[mt][r] = (z0[mt][r] + z1[mt][r]) * E[mt][r];
            if (p == BURNP && k == 0 && wq == 0) {
                const bool c0 = (s == 0);
#pragma unroll
                for (int mt = 0; mt < 4; ++mt)
#pragma unroll
                    for (int r = 0; r < 4; ++r)
                        w[mt][r] = c0 ? ILds[mt * 16 + g * 4 + r] * E[mt][r] : w[mt][r];
            }
            if (k == 7 && (p == BURNP - 1 || p == NPACK - 1)) {
                float swl = 0.f;
#pragma unroll
                for (int mt = 0; mt < 4; ++mt)
#pragma unroll
                    for (int r = 0; r < 4; ++r) swl += w[mt][r];
                swl += __shfl_xor(swl, 16);
                swl += __shfl_xor(swl, 32);
                swv = swl;
            }
#pragma unroll
            for (int kf = 0; kf < 2; ++kf)
#pragma unroll
                for (int j2 = 0; j2 < 4; ++j2) {
                    int mt = 2 * kf + (j2 >> 1), pr = j2 & 1;
                    float v0 = w[mt][2 * pr], v1 = w[mt][2 * pr + 1];
                    if (k == 7) { v0 *= SCALEF; v1 *= SCALEF; }
                    Bf[kf].u[j2] = pk_trunc(v0, v1);
                }
        }
        if (p == BURNP - 1) {
            const bool ch0 = (wq == 0) && (s == 0);
            S0v = ch0 ? ((float)(NPACK - 1 - BURNP) * RB)
                      : (__log2f(swv) + (float)(NPACK - BURNP) * RB);
        }
    }

    float tot = __log2f(swv) - S0v;
    tot += __shfl_xor(tot, 1);
    tot += __shfl_xor(tot, 2);
    tot += __shfl_xor(tot, 4);
    tot += __shfl_xor(tot, 8);
    if (lane == 0)
        atomicAdd(out + seq, tot * 0.6931471805599453f);
}

extern "C" void kernel_launch(void* const* d_in, const int* in_sizes, int n_in,
                              void* d_out, int out_size, void* d_ws, size_t ws_size,
                              hipStream_t stream) {
    const float* x  = (const float*)d_in[0];   // [B,T,M] one-hot
    const float* I  = (const float*)d_in[1];   // [1,S]
    const float* A  = (const float*)d_in[2];   // [S,S]
    const float* Bm = (const float*)d_in[3];   // [M,S]
    float* out = (float*)d_out;                // [B,1]

    hipMemsetAsync(out, 0, (size_t)out_size * sizeof(float), stream);

    const size_t need = (size_t)BATCH * T;     // 2 MB of o-bytes
    if (d_ws != nullptr && ws_size >= need) {
        unsigned char* ob = (unsigned char*)d_ws;
        hmm_extract<<<2048, 256, 0, stream>>>(x, ob);                            // 8192 waves, probe-shaped
        hmm_scan<<<(BATCH * 4) / WPB, WPB * 64, 0, stream>>>(
            (const unsigned long long*)ob, I, A, Bm, out);                       // 2048 waves
    } else {
        hmm_fused<<<(BATCH * 4) / WPB, WPB * 64, 0, stream>>>(x, I, A, Bm, out); // 2048 waves
    }
}

// Round 9
// 1294.996 us; speedup vs baseline: 1.1532x; 1.0244x over previous
//
#include <hip/hip_runtime.h>

// HMM forward (CgpHmmCell): B=512, T=4096, S=64, M=125.
// Round 26: FINAL REVERT to R18 (best verified: 1296.46us, absmax 0.0).
// Session conclusion: the kernel is AT the read-only HBM roofline.
// Evidence: R24's independent minimal probe (8192-wave grid-stride dwordx4
// read-reduce) measured 197.3us for the 1.05GB input = 5.3 TB/s read-only
// ceiling (copy's 6.3 counts R+W; fills write-only at 6.4). With the
// corrected overhead model (fill 670 + input restore ~350 + gaps ~80 =
// ~1100us), R18 fused = 196.5us -- equal to the probe within 0.5%. All six
// structural variants bracket it from above: R21 phased 223 (202+20), R25
// split 226 (205+21), R20 split 235 (213+21), R22 prod/cons 203, R19 spill
// 250. The scan is ~20us and rides inside the stream; extraction = mandatory
// 1.05GB read at ceiling. The earlier "extraction 62% of BW" theory was an
// artifact of overhead misattribution against a fictitious 6.3 TB/s target.
// Structure (unchanged from R18): per-wave 16 consecutive 64-row chunks,
// ping-pong bufP/bufQ distance-2 prefetch, dual-deposit boundary rows,
// Phase A = PRE+K+L (packs 0,1,8,9), in-loop passes feed packs 2..7,
// permuted-K MFMA contraction (16x16x32 bf16), constant 2^56/pack rescale,
// mass identity, chunk-0 exact I*E0 override, stride-68 BmL bank-phasing,
// one atomicAdd per wave. d_ws unused.

#define BATCH 512
#define T 4096
#define S 64
#define M 125
#define BMS 68     // BmL row stride in dwords: 68%32=4 -> 8 bank phases, 16B-aligned
#define NPACK 10   // 2 burn + 8 accumulate (chunk = 64 steps)
#define BURNP 2
#define WPB 4
#define RB 56.0f
#define SCALEF 7.205759403792794e16f   // 2^56

typedef __attribute__((ext_vector_type(8))) short bf16x8;
typedef __attribute__((ext_vector_type(4))) float f32x4;
typedef float f32x4u __attribute__((ext_vector_type(4), aligned(4)));  // 4-B-aligned vec4

union BFU { unsigned u[4]; bf16x8 v; };

__device__ __forceinline__ unsigned pk_trunc(float a, float b) {
    return (__float_as_uint(b) & 0xFFFF0000u) | (__float_as_uint(a) >> 16);
}
__device__ __forceinline__ unsigned pk_rne(float a, float b) {
    unsigned ua = __float_as_uint(a); ua += 0x7FFFu + ((ua >> 16) & 1u);
    unsigned ub = __float_as_uint(b); ub += 0x7FFFu + ((ub >> 16) & 1u);
    return (ub & 0xFFFF0000u) | (ua >> 16);
}

__global__ __launch_bounds__(256) void hmm_fused(const float* __restrict__ x,
                                                 const float* __restrict__ Iv,
                                                 const float* __restrict__ A,
                                                 const float* __restrict__ Bm,
                                                 float* __restrict__ out) {
    __shared__ __align__(16) float BmL[M * BMS];               // 34000 B, stride-68 rows
    __shared__ __align__(16) float ILds[S];
    __shared__ unsigned long long ulds[WPB * 16 * NPACK];      // 5120 B

    const int tid = threadIdx.x, wv = tid >> 6, lane = tid & 63;
    const int s = lane & 15, g = lane >> 4;

    for (int i = tid; i < M * S; i += WPB * 64)
        BmL[(i >> 6) * BMS + (i & 63)] = Bm[i];
    if (tid < S) ILds[tid] = Iv[tid];
    __syncthreads();

    // A^T fragments under pi: slot (kf,g,j2,e) holds A[p0+e][16mt+s],
    // p0 = 32kf + 16*(j2>>1) + 4g + 2*(j2&1).
    BFU Af[4][2];
#pragma unroll
    for (int mt = 0; mt < 4; ++mt)
#pragma unroll
        for (int kf = 0; kf < 2; ++kf)
#pragma unroll
            for (int j2 = 0; j2 < 4; ++j2) {
                int p0 = 32 * kf + 16 * (j2 >> 1) + 4 * g + 2 * (j2 & 1);
                Af[mt][kf].u[j2] = pk_rne(A[(size_t)p0 * S + mt * 16 + s],
                                          A[(size_t)(p0 + 1) * S + mt * 16 + s]);
            }

    const int W = blockIdx.x * WPB + wv;   // 0..2047
    const int seq = W >> 2, wq = W & 3;    // 4 waves per sequence
    const float* xs = x + (size_t)seq * T * M;
    unsigned long long* myu = &ulds[wv * 16 * NPACK];
    const int base = wq * 1024;            // wave's first row (seq-relative)

    const int rel = lane & 31, hf = lane >> 5;
    const unsigned coff = (rel < 31) ? 4u * (unsigned)rel : 121u;  // dword in row

    f32x4u bufP[8], bufQ[8];               // ping-pong: 2 x 16 rows in flight

    auto issue16 = [&](f32x4u (&bf)[8], int r0a, int r0b) {
#pragma unroll
        for (int j = 0; j < 4; ++j) {
            unsigned ra = (unsigned)((r0a + 2 * j + hf) * 125) + coff;
            unsigned rb = (unsigned)((r0b + 2 * j + hf) * 125) + coff;
            bf[j]     = *(const f32x4u*)&xs[ra];
            bf[4 + j] = *(const f32x4u*)&xs[rb];
        }
    };
    auto ext8 = [&](const f32x4u (&bf)[8], int b) -> unsigned long long {
        unsigned long long acc = 0;
#pragma unroll
        for (int j = 0; j < 4; ++j) {
            f32x4u v = bf[b * 4 + j];
            bool nz = (v.x != 0.f) || (v.y != 0.f) || (v.z != 0.f) || (v.w != 0.f);
            unsigned li = (v.x != 0.f) ? 0u : ((v.y != 0.f) ? 1u : ((v.z != 0.f) ? 2u : 3u));
            unsigned cand = coff + li;                 // dword index of first nz here
            unsigned long long m = __ballot(nz);       // one-hot => both halves nonzero
            unsigned l0 = (unsigned)__builtin_ctzll(m & 0xffffffffull);
            unsigned l1 = (unsigned)__builtin_ctzll(m >> 32);
            unsigned o0 = __builtin_amdgcn_readlane(cand, l0);        // row 2j
            unsigned o1 = __builtin_amdgcn_readlane(cand, 32 + l1);   // row 2j+1
            acc |= ((unsigned long long)o0 << (16 * j)) |
                   ((unsigned long long)o1 << (16 * j + 8));
        }
        return acc;
    };
    auto put = [&](int st, int pt, unsigned long long v) {
        if (lane == st) myu[st * NPACK + pt] = v;
    };

    // ---- Phase A: PRE (boundary burn) + K (rel 48..56) + L (rel 56..64) ----
    {
        int pa = base - 16, pb = base - 8;
        if (pa < 0) pa = 0;                // wq==0: garbage; chunk0 exact-init
        if (pb < 0) pb = 0;
        issue16(bufP, pa, pb);
        for (int gi = 0; gi <= 16; ++gi) {
            unsigned long long a0 = ext8(bufP, 0), a1 = ext8(bufP, 1);
            if (gi < 16) {                                   // issue next group
                int ni = gi + 1;
                if (ni <= 8) { int i = ni - 1; issue16(bufP, base + (2 * i) * 64 + 48, base + (2 * i + 1) * 64 + 48); }
                else         { int i = ni - 9; issue16(bufP, base + (2 * i) * 64 + 56, base + (2 * i + 1) * 64 + 56); }
            } else {
                issue16(bufP, base + 0, base + 64);          // step 0 (p0,k0)
            }
            if (gi == 0) {                                   // PRE -> (0,p0),(0,p1)
                put(0, 0, a0); put(0, 1, a1);
            } else if (gi <= 8) {                            // K: (c,p8) & (c+1,p0)
                int i = gi - 1;
                put(2 * i, 8, a0);     put(2 * i + 1, 0, a0);
                put(2 * i + 1, 8, a1); if (2 * i + 2 <= 15) put(2 * i + 2, 0, a1);
            } else {                                         // L: (c,p9) & (c+1,p1)
                int i = gi - 9;
                put(2 * i, 9, a0);     put(2 * i + 1, 1, a0);
                put(2 * i + 1, 9, a1); if (2 * i + 2 <= 15) put(2 * i + 2, 1, a1);
            }
        }
        issue16(bufQ, base + 128, base + 192);               // step 1 (p0,k1)
    }

    // ---- Phase B: scan packs 0..9; packs 0..5 interleave extraction ----
    BFU Bf[2];
#pragma unroll
    for (int kf = 0; kf < 2; ++kf)
#pragma unroll
        for (int j = 0; j < 4; ++j) Bf[kf].u[j] = 0x3F803F80u;  // 1.0 burn seed

    float S0v = 0.f, swv = 1.f;

    for (int p = 0; p < NPACK; ++p) {
        unsigned long long uv = myu[s * NPACK + p];   // this pack's o-bytes
        const bool exsl = (p < 6);
#pragma unroll
        for (int k = 0; k < 8; ++k) {
            // --- MFMA section first (issue, don't consume yet) ---
            const int o = (int)(uv & 255ull);
            uv >>= 8;
            const float* br = &BmL[o * BMS];          // per-stream row, bank-phased
            f32x4 E[4], z0[4], z1[4];
#pragma unroll
            for (int mt = 0; mt < 4; ++mt) {
                E[mt] = *(const f32x4*)&br[mt * 16 + g * 4];
                f32x4 zr = {0.f, 0.f, 0.f, 0.f};
                z0[mt] = __builtin_amdgcn_mfma_f32_16x16x32_bf16(Af[mt][0].v, Bf[0].v, zr, 0, 0, 0);
                z1[mt] = __builtin_amdgcn_mfma_f32_16x16x32_bf16(Af[mt][1].v, Bf[1].v, zr, 0, 0, 0);
            }
            // --- extraction (vmcnt wait overlaps MFMAs); distance-2 refill ---
            if (exsl) {
                unsigned long long a0, a1;
                // k is compile-time (unrolled): buffer parity = k&1
                if ((k & 1) == 0) { a0 = ext8(bufP, 0); a1 = ext8(bufP, 1); }
                else              { a0 = ext8(bufQ, 0); a1 = ext8(bufQ, 1); }
                int k2 = k + 2, p2 = p;
                bool ok = true;
                if (k2 >= 8) { k2 -= 8; p2 = p + 1; ok = (p2 < 6); }
                if (ok) {
                    int r0a = base + (2 * k2) * 64 + 8 * p2;
                    if ((k & 1) == 0) issue16(bufP, r0a, r0a + 64);
                    else              issue16(bufQ, r0a, r0a + 64);
                }
                put(2 * k, p + 2, a0);
                put(2 * k + 1, p + 2, a1);
            }
            // --- consume MFMA results ---
            float w[4][4];
#pragma unroll
            for (int mt = 0; mt < 4; ++mt)
#pragma unroll
                for (int r = 0; r < 4; ++r) w[mt][r] = (z0[mt][r] + z1[mt][r]) * E[mt][r];
            if (p == BURNP && k == 0 && wq == 0) {    // exact t=0 init of chunk 0
                const bool c0 = (s == 0);
#pragma unroll
                for (int mt = 0; mt < 4; ++mt)
#pragma unroll
                    for (int r = 0; r < 4; ++r)
                        w[mt][r] = c0 ? ILds[mt * 16 + g * 4 + r] * E[mt][r] : w[mt][r];
            }
            if (k == 7 && (p == BURNP - 1 || p == NPACK - 1)) {  // mass (pre-scale)
                float swl = 0.f;
#pragma unroll
                for (int mt = 0; mt < 4; ++mt)
#pragma unroll
                    for (int r = 0; r < 4; ++r) swl += w[mt][r];
                swl += __shfl_xor(swl, 16);
                swl += __shfl_xor(swl, 32);
                swv = swl;
            }
            // zero-shuffle C->B under pi; constant 2^56 rescale at k==7
#pragma unroll
            for (int kf = 0; kf < 2; ++kf)
#pragma unroll
                for (int j2 = 0; j2 < 4; ++j2) {
                    int mt = 2 * kf + (j2 >> 1), pr = j2 & 1;
                    float v0 = w[mt][2 * pr], v1 = w[mt][2 * pr + 1];
                    if (k == 7) { v0 *= SCALEF; v1 *= SCALEF; }
                    Bf[kf].u[j2] = pk_trunc(v0, v1);
                }
        }
        if (p == BURNP - 1) {
            // exponents: burn mass carries 1*RB, final carries (NPACK-1)*RB
            const bool ch0 = (wq == 0) && (s == 0);
            S0v = ch0 ? ((float)(NPACK - 1 - BURNP) * RB)
                      : (__log2f(swv) + (float)(NPACK - BURNP) * RB);
        }
    }

    float tot = __log2f(swv) - S0v;
    // sum over the 16 streams (s-dim); g-lanes hold duplicates
    tot += __shfl_xor(tot, 1);
    tot += __shfl_xor(tot, 2);
    tot += __shfl_xor(tot, 4);
    tot += __shfl_xor(tot, 8);
    if (lane == 0)
        atomicAdd(out + seq, tot * 0.6931471805599453f);
}

extern "C" void kernel_launch(void* const* d_in, const int* in_sizes, int n_in,
                              void* d_out, int out_size, void* d_ws, size_t ws_size,
                              hipStream_t stream) {
    const float* x  = (const float*)d_in[0];   // [B,T,M] one-hot
    const float* I  = (const float*)d_in[1];   // [1,S]
    const float* A  = (const float*)d_in[2];   // [S,S]
    const float* Bm = (const float*)d_in[3];   // [M,S]
    float* out = (float*)d_out;                // [B,1]
    (void)d_ws; (void)ws_size;                 // workspace unused (fully fused)

    hipMemsetAsync(out, 0, (size_t)out_size * sizeof(float), stream);
    hmm_fused<<<(BATCH * 4) / WPB, WPB * 64, 0, stream>>>(x, I, A, Bm, out);  // 2048 waves
}